// Round 8
// baseline (114.820 us; speedup 1.0000x reference)
//
#include <hip/hip_runtime.h>
#include <math.h>

// HeadAttention B=4, S=4096, D=1024, DK=DV=64, fp32 in/out, causal.
// Round 8: proj with ZERO synchronization. R5/R6/R7 all stalled at 4.5-9k
// cy/K-step regardless of staging mechanism -- the per-step s_barrier
// coupling 4 waves was the invariant cost. Now: 1-wave blocks, no LDS, no
// barriers. X loaded per-lane directly in A-fragment layout (128B-dense per
// row across the wave); W loaded per-lane from the fragment-linear wf
// (wave-contiguous 1KB bursts, L2-resident). Depth-1 A/B named-set
// prefetch; stalls are private per wave -> hidden by TLP (12 blocks/CU).
// Attention / combine / wsplit unchanged.

#define SEQ 4096
#define DIM 1024
#define HD  64
#define NB  4
#define NSPLIT 4

typedef __attribute__((ext_vector_type(4))) float    f32x4;
typedef __attribute__((ext_vector_type(8))) _Float16 f16x8;
typedef __attribute__((ext_vector_type(4))) _Float16 f16x4;

#define MFMA16 __builtin_amdgcn_mfma_f32_16x16x32_f16

// swizzled offset into a [row][64] f16 LDS tile (attn): XOR 16B-chunk with row&7
__device__ __forceinline__ int SW(int row, int k) {
  return row * 64 + (k ^ ((row & 7) << 3));
}

// ---------- W pre-split into fragment-linear layout ------------------------
// wf[((which*16+kt)*16 + slot)*512 + lane*8 + j]:
//   slot s=ks*4+ct (0..7) hi-frag, s+8 lo-frag;
//   element = W[k][col]*scale, col=ct*16+(lane&15), k=kt*64+ks*32+(lane>>4)*8+j
__global__ __launch_bounds__(256) void wsplit_kernel(
    const float* __restrict__ Wq, const float* __restrict__ Wk,
    const float* __restrict__ Wv, _Float16* __restrict__ wf)
{
  const int which = blockIdx.x;   // 0..2
  const int kt    = blockIdx.y;   // 0..15
  const float* __restrict__ W = (which == 0) ? Wq : (which == 1) ? Wk : Wv;
  const float scale = (which == 0) ? 0.18033688011112042f : 1.0f;  // log2(e)/8
  const size_t tb = ((size_t)which * 16 + kt) * 8192;
#pragma unroll
  for (int i = 0; i < 2; ++i) {
    const int pair = threadIdx.x + 256 * i;   // 0..511
    const int lane = pair & 63, f = pair >> 6;  // f = ks*4+ct in 0..7
    const int ks = f >> 2, ct = f & 3;
    const int col = ct * 16 + (lane & 15);
    const int k0 = kt * 64 + ks * 32 + (lane >> 4) * 8;
    f16x8 hv, lv;
#pragma unroll
    for (int j = 0; j < 8; ++j) {
      const float y = W[(size_t)(k0 + j) * HD + col] * scale;
      const _Float16 h = (_Float16)y;
      hv[j] = h;
      lv[j] = (_Float16)(y - (float)h);
    }
    *(f16x8*)&wf[tb + (size_t)f * 512 + lane * 8]       = hv;
    *(f16x8*)&wf[tb + (size_t)(8 + f) * 512 + lane * 8] = lv;
  }
}

// ---------- projection: barrier-free per-wave fp16x3 MFMA ------------------
// grid (1024, 3), 64 threads (1 wave = 16 output rows).
// Y = X[16384,1024] @ W[1024,64]. Per K-tile(64): 4 f32x4 X loads (A-frag
// layout, per-lane) + 16 f16x8 W frag loads (wave-contiguous from wf) +
// 24 MFMA + ~100 VALU split ops. No LDS, no barriers.
__global__ __launch_bounds__(64) void proj_kernel(
    const float* __restrict__ Xq, const float* __restrict__ Xk,
    const float* __restrict__ Xv,
    const _Float16* __restrict__ wf,
    _Float16* __restrict__ qh, _Float16* __restrict__ ql,
    _Float16* __restrict__ kh, _Float16* __restrict__ kl,
    _Float16* __restrict__ vt)
{
  const int which = blockIdx.y;
  const float* __restrict__ X = (which == 0) ? Xq : (which == 1) ? Xk : Xv;

  const int lane = threadIdx.x & 63;
  const int bm = blockIdx.x * 16;

  // A-frag: row = bm + (lane&15); k-slice base = (lane>>4)*8 within each 32
  const float* xp = X + (size_t)(bm + (lane & 15)) * DIM + ((lane >> 4) * 8);
  // W frags: slot s at wp + kt*8192 + s*512 (lane*8 contiguous)
  const _Float16* wp = wf + (size_t)which * 131072 + lane * 8;

  f32x4 acc[4] = {{0,0,0,0},{0,0,0,0},{0,0,0,0},{0,0,0,0}};

  // named staging sets (rule #20)
  f32x4 xA[4], xB[4];
  f16x8 whA[8], wlA[8], whB[8], wlB[8];

#define LOADT(xs, whs, wls, kt)                                           \
  do {                                                                    \
    xs[0] = *(const f32x4*)(xp + (kt) * 64);                              \
    xs[1] = *(const f32x4*)(xp + (kt) * 64 + 4);                          \
    xs[2] = *(const f32x4*)(xp + (kt) * 64 + 32);                         \
    xs[3] = *(const f32x4*)(xp + (kt) * 64 + 36);                         \
    _Pragma("unroll")                                                     \
    for (int s = 0; s < 8; ++s) {                                         \
      whs[s] = *(const f16x8*)(wp + (size_t)(kt) * 8192 + s * 512);       \
      wls[s] = *(const f16x8*)(wp + (size_t)(kt) * 8192 + (8 + s) * 512); \
    }                                                                     \
  } while (0)

#define COMPUTET(xs, whs, wls)                                            \
  do {                                                                    \
    _Pragma("unroll")                                                     \
    for (int ks = 0; ks < 2; ++ks) {                                      \
      f16x8 xh, xl;                                                       \
      _Pragma("unroll")                                                   \
      for (int j = 0; j < 4; ++j) {                                       \
        const float v0 = xs[2 * ks][j];                                   \
        const _Float16 h0 = (_Float16)v0;                                 \
        xh[j] = h0; xl[j] = (_Float16)(v0 - (float)h0);                   \
        const float v1 = xs[2 * ks + 1][j];                               \
        const _Float16 h1 = (_Float16)v1;                                 \
        xh[j + 4] = h1; xl[j + 4] = (_Float16)(v1 - (float)h1);           \
      }                                                                   \
      _Pragma("unroll")                                                   \
      for (int ct = 0; ct < 4; ++ct) {                                    \
        acc[ct] = MFMA16(xh, whs[ks * 4 + ct], acc[ct], 0, 0, 0);         \
        acc[ct] = MFMA16(xl, whs[ks * 4 + ct], acc[ct], 0, 0, 0);         \
        acc[ct] = MFMA16(xh, wls[ks * 4 + ct], acc[ct], 0, 0, 0);         \
      }                                                                   \
    }                                                                     \
  } while (0)

  LOADT(xA, whA, wlA, 0);
#pragma unroll 1
  for (int kt = 0; kt < DIM / 64; kt += 2) {
    LOADT(xB, whB, wlB, kt + 1);
    COMPUTET(xA, whA, wlA);
    if (kt + 2 < DIM / 64) LOADT(xA, whA, wlA, kt + 2);
    COMPUTET(xB, whB, wlB);
  }
#undef LOADT
#undef COMPUTET

  // epilogue: C layout col=lane&15, row=(lane>>4)*4+r
  const size_t orow0 = (size_t)bm + (lane >> 4) * 4;
  if (which < 2) {
    _Float16* oh = (which == 0) ? qh : kh;
    _Float16* ol = (which == 0) ? ql : kl;
#pragma unroll
    for (int ct = 0; ct < 4; ++ct)
#pragma unroll
      for (int r = 0; r < 4; ++r) {
        const float y = acc[ct][r];
        const _Float16 h = (_Float16)y;
        const size_t idx = (orow0 + r) * HD + ct * 16 + (lane & 15);
        oh[idx] = h;
        ol[idx] = (_Float16)(y - (float)h);
      }
  } else {
    const int batch = (int)(orow0 >> 12);
    const int pos = (int)(orow0 & 4095);
#pragma unroll
    for (int ct = 0; ct < 4; ++ct) {
      f16x4 hv;
#pragma unroll
      for (int r = 0; r < 4; ++r) hv[r] = (_Float16)acc[ct][r];
      *(f16x4*)&vt[((size_t)batch * HD + ct * 16 + (lane & 15)) * SEQ + pos] = hv;
    }
  }
}

// ---------- flash attention, fp16x3 QK + f16 PV, split-4 partials ----------
// grid (128, 4): x -> pair p=x>>2 (q-blocks p and 63-p), parity s=x&3.
__global__ __launch_bounds__(256) void attn_kernel(
    const _Float16* __restrict__ qh, const _Float16* __restrict__ ql,
    const _Float16* __restrict__ kh, const _Float16* __restrict__ kl,
    const _Float16* __restrict__ vt,
    _Float16* __restrict__ opart, float* __restrict__ mlp)
{
  __shared__ __attribute__((aligned(16))) _Float16 Ksh[64 * 64];
  __shared__ __attribute__((aligned(16))) _Float16 Ksl[64 * 64];
  __shared__ __attribute__((aligned(16))) _Float16 Vs [64 * 64];
  __shared__ __attribute__((aligned(16))) _Float16 Pt [64 * 64];

  const int t = threadIdx.x, lane = t & 63, w = t >> 6;
  const int b = blockIdx.y;
  const int p = blockIdx.x >> 2, s = blockIdx.x & 3;
  const size_t bS = (size_t)b * SEQ;

  for (int sel = 0; sel < 2; ++sel) {
    const int qb = sel ? (63 - p) : p;
    const int qrow0 = qb * 64 + w * 16;
    const int nt = (qb >= s) ? ((qb - s) >> 2) + 1 : 0;  // kv tiles ≡ s mod 4

    float m[4] = {-INFINITY, -INFINITY, -INFINITY, -INFINITY};
    float lsum[4] = {0.f, 0.f, 0.f, 0.f};
    f32x4 o[4] = {{0,0,0,0},{0,0,0,0},{0,0,0,0},{0,0,0,0}};

    if (nt > 0) {
      const _Float16* qhp = qh + (bS + qrow0 + (lane & 15)) * HD + ((lane >> 4) * 8);
      const _Float16* qlp = ql + (bS + qrow0 + (lane & 15)) * HD + ((lane >> 4) * 8);
      f16x8 qhf[2], qlf[2];
      qhf[0] = *(const f16x8*)(qhp);      qhf[1] = *(const f16x8*)(qhp + 32);
      qlf[0] = *(const f16x8*)(qlp);      qlf[1] = *(const f16x8*)(qlp + 32);

      for (int i = 0; i < nt; ++i) {
        const int kt = s + 4 * i;
        const int j0 = kt * 64;

        __syncthreads();  // previous tile's LDS reads complete
#pragma unroll
        for (int c = 0; c < 2; ++c) {
          const int lin = t + 256 * c;
          const int row = lin >> 3, d8 = (lin & 7) * 8;
          const int dst = SW(row, d8);
          *(f16x8*)&Ksh[dst] = *(const f16x8*)&kh[(bS + j0 + row) * HD + d8];
          *(f16x8*)&Ksl[dst] = *(const f16x8*)&kl[(bS + j0 + row) * HD + d8];
          *(f16x8*)&Vs[dst]  = *(const f16x8*)&vt[((size_t)b * HD + row) * SEQ + j0 + d8];
        }
        __syncthreads();

        // ---- QK^T: fp16x3
        f32x4 sacc[4] = {{0,0,0,0},{0,0,0,0},{0,0,0,0},{0,0,0,0}};
#pragma unroll
        for (int ks = 0; ks < 2; ++ks)
#pragma unroll
          for (int kt4 = 0; kt4 < 4; ++kt4) {
            const int ba = SW(kt4 * 16 + (lane & 15), ks * 32 + (lane >> 4) * 8);
            f16x8 bh = *(const f16x8*)&Ksh[ba];
            f16x8 bl = *(const f16x8*)&Ksl[ba];
            sacc[kt4] = MFMA16(qhf[ks], bh, sacc[kt4], 0, 0, 0);
            sacc[kt4] = MFMA16(qlf[ks], bh, sacc[kt4], 0, 0, 0);
            sacc[kt4] = MFMA16(qhf[ks], bl, sacc[kt4], 0, 0, 0);
          }

        // ---- causal mask on the diagonal tile
        if (kt == qb) {
#pragma unroll
          for (int kt4 = 0; kt4 < 4; ++kt4) {
            const int key = j0 + kt4 * 16 + (lane & 15);
#pragma unroll
            for (int r = 0; r < 4; ++r)
              if (key > qrow0 + (lane >> 4) * 4 + r) sacc[kt4][r] = -INFINITY;
          }
        }

        // ---- online softmax (exp2 domain), P -> LDS f16
        float alf[4];
#pragma unroll
        for (int r = 0; r < 4; ++r) {
          float mx = fmaxf(fmaxf(sacc[0][r], sacc[1][r]),
                           fmaxf(sacc[2][r], sacc[3][r]));
          mx = fmaxf(mx, __shfl_xor(mx, 1));
          mx = fmaxf(mx, __shfl_xor(mx, 2));
          mx = fmaxf(mx, __shfl_xor(mx, 4));
          mx = fmaxf(mx, __shfl_xor(mx, 8));
          const float mn = fmaxf(m[r], mx);
          const float al = exp2f(m[r] - mn);
          const int prow = w * 16 + (lane >> 4) * 4 + r;
          float ps = 0.f;
#pragma unroll
          for (int kt4 = 0; kt4 < 4; ++kt4) {
            const _Float16 ph = (_Float16)exp2f(sacc[kt4][r] - mn);
            ps += (float)ph;
            Pt[SW(prow, kt4 * 16 + (lane & 15))] = ph;
          }
          ps += __shfl_xor(ps, 1);
          ps += __shfl_xor(ps, 2);
          ps += __shfl_xor(ps, 4);
          ps += __shfl_xor(ps, 8);
          lsum[r] = lsum[r] * al + ps;
          m[r] = mn;
          alf[r] = al;
        }
        const f32x4 av = {alf[0], alf[1], alf[2], alf[3]};
#pragma unroll
        for (int ct = 0; ct < 4; ++ct) o[ct] *= av;

        // ---- PV (per-wave Pt region)
#pragma unroll
        for (int ks = 0; ks < 2; ++ks) {
          f16x8 pa = *(const f16x8*)&Pt[SW(w * 16 + (lane & 15),
                                           ks * 32 + (lane >> 4) * 8)];
#pragma unroll
          for (int ct = 0; ct < 4; ++ct) {
            f16x8 vb = *(const f16x8*)&Vs[SW(ct * 16 + (lane & 15),
                                             ks * 32 + (lane >> 4) * 8)];
            o[ct] = MFMA16(pa, vb, o[ct], 0, 0, 0);
          }
        }
      }
    }

    // ---- write partials: normalized o (f16) + (m, l) f32
    f32x4 invv;
#pragma unroll
    for (int r = 0; r < 4; ++r) invv[r] = (nt > 0) ? 1.0f / lsum[r] : 0.0f;
    const size_t ridx0 = (size_t)(b * NSPLIT + s) * SEQ + qrow0 + (lane >> 4) * 4;
#pragma unroll
    for (int ct = 0; ct < 4; ++ct)
#pragma unroll
      for (int r = 0; r < 4; ++r)
        opart[(ridx0 + r) * HD + ct * 16 + (lane & 15)] =
            (_Float16)(o[ct][r] * invv[r]);
    if ((lane & 15) == 0) {
#pragma unroll
      for (int r = 0; r < 4; ++r) {
        mlp[(ridx0 + r) * 2]     = m[r];
        mlp[(ridx0 + r) * 2 + 1] = lsum[r];
      }
    }
  }
}

// ---------- combine the 4 kv-parity partials -------------------------------
__global__ __launch_bounds__(256) void combine_kernel(
    const _Float16* __restrict__ opart, const float* __restrict__ mlp,
    float* __restrict__ out)
{
  const int g = blockIdx.x * 256 + threadIdx.x;   // 262144
  const int row = g >> 4;
  const int cq = (g & 15) * 4;
  const int b = row >> 12, pos = row & 4095;

  float mv[4], lv[4], msx = -INFINITY;
#pragma unroll
  for (int s = 0; s < 4; ++s) {
    const size_t ri = (size_t)(b * NSPLIT + s) * SEQ + pos;
    mv[s] = mlp[ri * 2];
    lv[s] = mlp[ri * 2 + 1];
    msx = fmaxf(msx, mv[s]);
  }
  f32x4 num = {0.f, 0.f, 0.f, 0.f};
  float L = 0.f;
#pragma unroll
  for (int s = 0; s < 4; ++s) {
    const float wgt = lv[s] * exp2f(mv[s] - msx);
    L += wgt;
    const size_t ri = (size_t)(b * NSPLIT + s) * SEQ + pos;
    const f16x4 ov = *(const f16x4*)&opart[ri * HD + cq];
#pragma unroll
    for (int j = 0; j < 4; ++j) num[j] += wgt * (float)ov[j];
  }
  const float inv = 1.0f / L;
  f32x4 res = {num[0] * inv, num[1] * inv, num[2] * inv, num[3] * inv};
  *(f32x4*)&out[(size_t)row * HD + cq] = res;
}

extern "C" void kernel_launch(void* const* d_in, const int* in_sizes, int n_in,
                              void* d_out, int out_size, void* d_ws, size_t ws_size,
                              hipStream_t stream) {
  const float* query = (const float*)d_in[0];
  const float* key   = (const float*)d_in[1];
  const float* value = (const float*)d_in[2];
  const float* Wq    = (const float*)d_in[3];
  const float* Wk    = (const float*)d_in[4];
  const float* Wv    = (const float*)d_in[5];
  // d_in[6]: causal mask, handled analytically.

  float* out = (float*)d_out;

  _Float16* qh  = (_Float16*)d_ws;
  _Float16* ql  = qh  + (size_t)NB * SEQ * HD;
  _Float16* kh  = ql  + (size_t)NB * SEQ * HD;
  _Float16* kl  = kh  + (size_t)NB * SEQ * HD;
  _Float16* vt  = kl  + (size_t)NB * SEQ * HD;           // [b][64][4096]
  _Float16* wf  = vt  + (size_t)NB * SEQ * HD;           // [3][16][16][512]
  _Float16* opart = wf + (size_t)3 * 16 * 8192;          // [b*4+s][4096][64]
  float* mlp = (float*)(opart + (size_t)NB * NSPLIT * SEQ * HD);

  wsplit_kernel<<<dim3(3, 16), 256, 0, stream>>>(Wq, Wk, Wv, wf);
  proj_kernel<<<dim3(1024, 3), 64, 0, stream>>>(query, key, value, wf,
                                                qh, ql, kh, kl, vt);
  attn_kernel<<<dim3(128, NB), 256, 0, stream>>>(qh, ql, kh, kl, vt, opart, mlp);
  combine_kernel<<<1024, 256, 0, stream>>>(opart, mlp, out);
}

// Round 9
// 108.831 us; speedup vs baseline: 1.0550x; 1.0550x over previous
//
#include <hip/hip_runtime.h>
#include <math.h>

// HeadAttention B=4, S=4096, D=1024, DK=DV=64, fp32 in/out, causal.
// Round 9: proj staging loads moved to inline-asm global_load_dwordx4 with
// manually counted s_waitcnt vmcnt(N). R4/R6/R7/R8 all failed the same way:
// the HIP scheduler sinks compiler-generated loads to their uses (VGPR
// pinned at 88, serialized load groups, ~17k cy per K-tile). Volatile asm
// loads cannot be sunk and the backend's waitcnt pass doesn't track them,
// so the counted-wait depth-2 pipeline finally exists in the emitted code.
// Structure is R8's barrier-free 1-wave-per-block proj (no LDS, no syncs).
// vmcnt ledger: 40 outstanding after issue, wait(20) before each compute,
// epilogue wait(20)/compute/wait(0)/compute. No other VMEM in the loop.
// Attention / combine / wsplit unchanged.

#define SEQ 4096
#define DIM 1024
#define HD  64
#define NB  4
#define NSPLIT 4

typedef __attribute__((ext_vector_type(4))) float    f32x4;
typedef __attribute__((ext_vector_type(8))) _Float16 f16x8;
typedef __attribute__((ext_vector_type(4))) _Float16 f16x4;

#define MFMA16 __builtin_amdgcn_mfma_f32_16x16x32_f16

// swizzled offset into a [row][64] f16 LDS tile (attn): XOR 16B-chunk with row&7
__device__ __forceinline__ int SW(int row, int k) {
  return row * 64 + (k ^ ((row & 7) << 3));
}

// 16B asm load, compile-time byte offset; "=&v" early-clobber so the dest
// tuple never aliases the address pair.
#define GLD16(dst, ptr, imm)                                        \
  asm volatile("global_load_dwordx4 %0, %1, off offset:" #imm      \
               : "=&v"(dst) : "v"(ptr))

// counted wait + scheduling fence (rule #18)
#define VMWAIT(n)                                                   \
  do {                                                              \
    asm volatile("s_waitcnt vmcnt(" #n ")" ::: "memory");           \
    __builtin_amdgcn_sched_barrier(0);                              \
  } while (0)

// ---------- W pre-split into fragment-linear layout ------------------------
// wf[((which*16+kt)*16 + slot)*512 + lane*8 + j]:
//   slot s=ks*4+ct (0..7) hi-frag, s+8 lo-frag;
//   element = W[k][col]*scale, col=ct*16+(lane&15), k=kt*64+ks*32+(lane>>4)*8+j
__global__ __launch_bounds__(256) void wsplit_kernel(
    const float* __restrict__ Wq, const float* __restrict__ Wk,
    const float* __restrict__ Wv, _Float16* __restrict__ wf)
{
  const int which = blockIdx.x;   // 0..2
  const int kt    = blockIdx.y;   // 0..15
  const float* __restrict__ W = (which == 0) ? Wq : (which == 1) ? Wk : Wv;
  const float scale = (which == 0) ? 0.18033688011112042f : 1.0f;  // log2(e)/8
  const size_t tb = ((size_t)which * 16 + kt) * 8192;
#pragma unroll
  for (int i = 0; i < 2; ++i) {
    const int pair = threadIdx.x + 256 * i;   // 0..511
    const int lane = pair & 63, f = pair >> 6;  // f = ks*4+ct in 0..7
    const int ks = f >> 2, ct = f & 3;
    const int col = ct * 16 + (lane & 15);
    const int k0 = kt * 64 + ks * 32 + (lane >> 4) * 8;
    f16x8 hv, lv;
#pragma unroll
    for (int j = 0; j < 8; ++j) {
      const float y = W[(size_t)(k0 + j) * HD + col] * scale;
      const _Float16 h = (_Float16)y;
      hv[j] = h;
      lv[j] = (_Float16)(y - (float)h);
    }
    *(f16x8*)&wf[tb + (size_t)f * 512 + lane * 8]       = hv;
    *(f16x8*)&wf[tb + (size_t)(8 + f) * 512 + lane * 8] = lv;
  }
}

// ---------- projection: barrier-free, asm-pipelined fp16x3 MFMA ------------
// grid (1024, 3), 64 threads (1 wave = 16 output rows).
// Per K-tile: 20 asm loads (4 X f32x4 + 16 W f16x8) + 24 MFMA + ~100 VALU.
// No LDS, no barriers; depth-2 named-set pipeline with counted vmcnt.
__global__ __launch_bounds__(64, 2) void proj_kernel(
    const float* __restrict__ Xq, const float* __restrict__ Xk,
    const float* __restrict__ Xv,
    const _Float16* __restrict__ wf,
    _Float16* __restrict__ qh, _Float16* __restrict__ ql,
    _Float16* __restrict__ kh, _Float16* __restrict__ kl,
    _Float16* __restrict__ vt)
{
  const int which = blockIdx.y;
  const float* __restrict__ X = (which == 0) ? Xq : (which == 1) ? Xk : Xv;

  const int lane = threadIdx.x & 63;
  const int bm = blockIdx.x * 16;

  // A-frag: row = bm + (lane&15); k-slice base = (lane>>4)*8 within each 32
  const float* xp = X + (size_t)(bm + (lane & 15)) * DIM + ((lane >> 4) * 8);
  // W frags: slot s at byte offset s*1024 from tile base; lane*8 contiguous
  const _Float16* wp = wf + (size_t)which * 131072 + lane * 8;

  f32x4 acc[4] = {{0,0,0,0},{0,0,0,0},{0,0,0,0},{0,0,0,0}};

  // named staging sets (rule #20)
  f32x4 xA[4], xB[4];
  f16x8 whA[8], wlA[8], whB[8], wlB[8];

  // 20 ordered volatile loads per tile: X {0,16,128,144}B; W 4 groups x
  // {0,1024,2048,3072}B (slots 0-7 hi, 8-15 lo at byte s*1024).
#define LOADT(xs, whs, wls, kt)                                      \
  do {                                                               \
    const float* xb = xp + (kt) * 64;                                \
    GLD16(xs[0], xb, 0);                                             \
    GLD16(xs[1], xb, 16);                                            \
    GLD16(xs[2], xb, 128);                                           \
    GLD16(xs[3], xb, 144);                                           \
    const _Float16* wb0 = wp + (size_t)(kt) * 8192;                  \
    const _Float16* wb1 = wb0 + 2048;                                \
    const _Float16* wb2 = wb0 + 4096;                                \
    const _Float16* wb3 = wb0 + 6144;                                \
    GLD16(whs[0], wb0, 0);                                           \
    GLD16(whs[1], wb0, 1024);                                        \
    GLD16(whs[2], wb0, 2048);                                        \
    GLD16(whs[3], wb0, 3072);                                        \
    GLD16(whs[4], wb1, 0);                                           \
    GLD16(whs[5], wb1, 1024);                                        \
    GLD16(whs[6], wb1, 2048);                                        \
    GLD16(whs[7], wb1, 3072);                                        \
    GLD16(wls[0], wb2, 0);                                           \
    GLD16(wls[1], wb2, 1024);                                        \
    GLD16(wls[2], wb2, 2048);                                        \
    GLD16(wls[3], wb2, 3072);                                        \
    GLD16(wls[4], wb3, 0);                                           \
    GLD16(wls[5], wb3, 1024);                                        \
    GLD16(wls[6], wb3, 2048);                                        \
    GLD16(wls[7], wb3, 3072);                                        \
  } while (0)

#define COMPUTET(xs, whs, wls)                                            \
  do {                                                                    \
    _Pragma("unroll")                                                     \
    for (int ks = 0; ks < 2; ++ks) {                                      \
      f16x8 xh, xl;                                                       \
      _Pragma("unroll")                                                   \
      for (int j = 0; j < 4; ++j) {                                       \
        const float v0 = xs[2 * ks][j];                                   \
        const _Float16 h0 = (_Float16)v0;                                 \
        xh[j] = h0; xl[j] = (_Float16)(v0 - (float)h0);                   \
        const float v1 = xs[2 * ks + 1][j];                               \
        const _Float16 h1 = (_Float16)v1;                                 \
        xh[j + 4] = h1; xl[j + 4] = (_Float16)(v1 - (float)h1);           \
      }                                                                   \
      _Pragma("unroll")                                                   \
      for (int ct = 0; ct < 4; ++ct) {                                    \
        acc[ct] = MFMA16(xh, whs[ks * 4 + ct], acc[ct], 0, 0, 0);         \
        acc[ct] = MFMA16(xl, whs[ks * 4 + ct], acc[ct], 0, 0, 0);         \
        acc[ct] = MFMA16(xh, wls[ks * 4 + ct], acc[ct], 0, 0, 0);         \
      }                                                                   \
    }                                                                     \
  } while (0)

  // prologue: tiles 0,1 in flight (outstanding = 40)
  LOADT(xA, whA, wlA, 0);
  LOADT(xB, whB, wlB, 1);

#pragma unroll 1
  for (int kt = 0; kt < 14; kt += 2) {
    VMWAIT(20);                       // tile kt (set A) complete
    COMPUTET(xA, whA, wlA);
    LOADT(xA, whA, wlA, kt + 2);      // outstanding back to 40
    VMWAIT(20);                       // tile kt+1 (set B) complete
    COMPUTET(xB, whB, wlB);
    LOADT(xB, whB, wlB, kt + 3);      // outstanding back to 40
  }
  VMWAIT(20);                         // tile 14 complete
  COMPUTET(xA, whA, wlA);
  VMWAIT(0);                          // tile 15 complete
  COMPUTET(xB, whB, wlB);
#undef LOADT
#undef COMPUTET

  // epilogue: C layout col=lane&15, row=(lane>>4)*4+r
  const size_t orow0 = (size_t)bm + (lane >> 4) * 4;
  if (which < 2) {
    _Float16* oh = (which == 0) ? qh : kh;
    _Float16* ol = (which == 0) ? ql : kl;
#pragma unroll
    for (int ct = 0; ct < 4; ++ct)
#pragma unroll
      for (int r = 0; r < 4; ++r) {
        const float y = acc[ct][r];
        const _Float16 h = (_Float16)y;
        const size_t idx = (orow0 + r) * HD + ct * 16 + (lane & 15);
        oh[idx] = h;
        ol[idx] = (_Float16)(y - (float)h);
      }
  } else {
    const int batch = (int)(orow0 >> 12);
    const int pos = (int)(orow0 & 4095);
#pragma unroll
    for (int ct = 0; ct < 4; ++ct) {
      f16x4 hv;
#pragma unroll
      for (int r = 0; r < 4; ++r) hv[r] = (_Float16)acc[ct][r];
      *(f16x4*)&vt[((size_t)batch * HD + ct * 16 + (lane & 15)) * SEQ + pos] = hv;
    }
  }
}

// ---------- flash attention, fp16x3 QK + f16 PV, split-4 partials ----------
// grid (128, 4): x -> pair p=x>>2 (q-blocks p and 63-p), parity s=x&3.
__global__ __launch_bounds__(256) void attn_kernel(
    const _Float16* __restrict__ qh, const _Float16* __restrict__ ql,
    const _Float16* __restrict__ kh, const _Float16* __restrict__ kl,
    const _Float16* __restrict__ vt,
    _Float16* __restrict__ opart, float* __restrict__ mlp)
{
  __shared__ __attribute__((aligned(16))) _Float16 Ksh[64 * 64];
  __shared__ __attribute__((aligned(16))) _Float16 Ksl[64 * 64];
  __shared__ __attribute__((aligned(16))) _Float16 Vs [64 * 64];
  __shared__ __attribute__((aligned(16))) _Float16 Pt [64 * 64];

  const int t = threadIdx.x, lane = t & 63, w = t >> 6;
  const int b = blockIdx.y;
  const int p = blockIdx.x >> 2, s = blockIdx.x & 3;
  const size_t bS = (size_t)b * SEQ;

  for (int sel = 0; sel < 2; ++sel) {
    const int qb = sel ? (63 - p) : p;
    const int qrow0 = qb * 64 + w * 16;
    const int nt = (qb >= s) ? ((qb - s) >> 2) + 1 : 0;  // kv tiles ≡ s mod 4

    float m[4] = {-INFINITY, -INFINITY, -INFINITY, -INFINITY};
    float lsum[4] = {0.f, 0.f, 0.f, 0.f};
    f32x4 o[4] = {{0,0,0,0},{0,0,0,0},{0,0,0,0},{0,0,0,0}};

    if (nt > 0) {
      const _Float16* qhp = qh + (bS + qrow0 + (lane & 15)) * HD + ((lane >> 4) * 8);
      const _Float16* qlp = ql + (bS + qrow0 + (lane & 15)) * HD + ((lane >> 4) * 8);
      f16x8 qhf[2], qlf[2];
      qhf[0] = *(const f16x8*)(qhp);      qhf[1] = *(const f16x8*)(qhp + 32);
      qlf[0] = *(const f16x8*)(qlp);      qlf[1] = *(const f16x8*)(qlp + 32);

      for (int i = 0; i < nt; ++i) {
        const int kt = s + 4 * i;
        const int j0 = kt * 64;

        __syncthreads();  // previous tile's LDS reads complete
#pragma unroll
        for (int c = 0; c < 2; ++c) {
          const int lin = t + 256 * c;
          const int row = lin >> 3, d8 = (lin & 7) * 8;
          const int dst = SW(row, d8);
          *(f16x8*)&Ksh[dst] = *(const f16x8*)&kh[(bS + j0 + row) * HD + d8];
          *(f16x8*)&Ksl[dst] = *(const f16x8*)&kl[(bS + j0 + row) * HD + d8];
          *(f16x8*)&Vs[dst]  = *(const f16x8*)&vt[((size_t)b * HD + row) * SEQ + j0 + d8];
        }
        __syncthreads();

        // ---- QK^T: fp16x3
        f32x4 sacc[4] = {{0,0,0,0},{0,0,0,0},{0,0,0,0},{0,0,0,0}};
#pragma unroll
        for (int ks = 0; ks < 2; ++ks)
#pragma unroll
          for (int kt4 = 0; kt4 < 4; ++kt4) {
            const int ba = SW(kt4 * 16 + (lane & 15), ks * 32 + (lane >> 4) * 8);
            f16x8 bh = *(const f16x8*)&Ksh[ba];
            f16x8 bl = *(const f16x8*)&Ksl[ba];
            sacc[kt4] = MFMA16(qhf[ks], bh, sacc[kt4], 0, 0, 0);
            sacc[kt4] = MFMA16(qlf[ks], bh, sacc[kt4], 0, 0, 0);
            sacc[kt4] = MFMA16(qhf[ks], bl, sacc[kt4], 0, 0, 0);
          }

        // ---- causal mask on the diagonal tile
        if (kt == qb) {
#pragma unroll
          for (int kt4 = 0; kt4 < 4; ++kt4) {
            const int key = j0 + kt4 * 16 + (lane & 15);
#pragma unroll
            for (int r = 0; r < 4; ++r)
              if (key > qrow0 + (lane >> 4) * 4 + r) sacc[kt4][r] = -INFINITY;
          }
        }

        // ---- online softmax (exp2 domain), P -> LDS f16
        float alf[4];
#pragma unroll
        for (int r = 0; r < 4; ++r) {
          float mx = fmaxf(fmaxf(sacc[0][r], sacc[1][r]),
                           fmaxf(sacc[2][r], sacc[3][r]));
          mx = fmaxf(mx, __shfl_xor(mx, 1));
          mx = fmaxf(mx, __shfl_xor(mx, 2));
          mx = fmaxf(mx, __shfl_xor(mx, 4));
          mx = fmaxf(mx, __shfl_xor(mx, 8));
          const float mn = fmaxf(m[r], mx);
          const float al = exp2f(m[r] - mn);
          const int prow = w * 16 + (lane >> 4) * 4 + r;
          float ps = 0.f;
#pragma unroll
          for (int kt4 = 0; kt4 < 4; ++kt4) {
            const _Float16 ph = (_Float16)exp2f(sacc[kt4][r] - mn);
            ps += (float)ph;
            Pt[SW(prow, kt4 * 16 + (lane & 15))] = ph;
          }
          ps += __shfl_xor(ps, 1);
          ps += __shfl_xor(ps, 2);
          ps += __shfl_xor(ps, 4);
          ps += __shfl_xor(ps, 8);
          lsum[r] = lsum[r] * al + ps;
          m[r] = mn;
          alf[r] = al;
        }
        const f32x4 av = {alf[0], alf[1], alf[2], alf[3]};
#pragma unroll
        for (int ct = 0; ct < 4; ++ct) o[ct] *= av;

        // ---- PV (per-wave Pt region)
#pragma unroll
        for (int ks = 0; ks < 2; ++ks) {
          f16x8 pa = *(const f16x8*)&Pt[SW(w * 16 + (lane & 15),
                                           ks * 32 + (lane >> 4) * 8)];
#pragma unroll
          for (int ct = 0; ct < 4; ++ct) {
            f16x8 vb = *(const f16x8*)&Vs[SW(ct * 16 + (lane & 15),
                                             ks * 32 + (lane >> 4) * 8)];
            o[ct] = MFMA16(pa, vb, o[ct], 0, 0, 0);
          }
        }
      }
    }

    // ---- write partials: normalized o (f16) + (m, l) f32
    f32x4 invv;
#pragma unroll
    for (int r = 0; r < 4; ++r) invv[r] = (nt > 0) ? 1.0f / lsum[r] : 0.0f;
    const size_t ridx0 = (size_t)(b * NSPLIT + s) * SEQ + qrow0 + (lane >> 4) * 4;
#pragma unroll
    for (int ct = 0; ct < 4; ++ct)
#pragma unroll
      for (int r = 0; r < 4; ++r)
        opart[(ridx0 + r) * HD + ct * 16 + (lane & 15)] =
            (_Float16)(o[ct][r] * invv[r]);
    if ((lane & 15) == 0) {
#pragma unroll
      for (int r = 0; r < 4; ++r) {
        mlp[(ridx0 + r) * 2]     = m[r];
        mlp[(ridx0 + r) * 2 + 1] = lsum[r];
      }
    }
  }
}

// ---------- combine the 4 kv-parity partials -------------------------------
__global__ __launch_bounds__(256) void combine_kernel(
    const _Float16* __restrict__ opart, const float* __restrict__ mlp,
    float* __restrict__ out)
{
  const int g = blockIdx.x * 256 + threadIdx.x;   // 262144
  const int row = g >> 4;
  const int cq = (g & 15) * 4;
  const int b = row >> 12, pos = row & 4095;

  float mv[4], lv[4], msx = -INFINITY;
#pragma unroll
  for (int s = 0; s < 4; ++s) {
    const size_t ri = (size_t)(b * NSPLIT + s) * SEQ + pos;
    mv[s] = mlp[ri * 2];
    lv[s] = mlp[ri * 2 + 1];
    msx = fmaxf(msx, mv[s]);
  }
  f32x4 num = {0.f, 0.f, 0.f, 0.f};
  float L = 0.f;
#pragma unroll
  for (int s = 0; s < 4; ++s) {
    const float wgt = lv[s] * exp2f(mv[s] - msx);
    L += wgt;
    const size_t ri = (size_t)(b * NSPLIT + s) * SEQ + pos;
    const f16x4 ov = *(const f16x4*)&opart[ri * HD + cq];
#pragma unroll
    for (int j = 0; j < 4; ++j) num[j] += wgt * (float)ov[j];
  }
  const float inv = 1.0f / L;
  f32x4 res = {num[0] * inv, num[1] * inv, num[2] * inv, num[3] * inv};
  *(f32x4*)&out[(size_t)row * HD + cq] = res;
}

extern "C" void kernel_launch(void* const* d_in, const int* in_sizes, int n_in,
                              void* d_out, int out_size, void* d_ws, size_t ws_size,
                              hipStream_t stream) {
  const float* query = (const float*)d_in[0];
  const float* key   = (const float*)d_in[1];
  const float* value = (const float*)d_in[2];
  const float* Wq    = (const float*)d_in[3];
  const float* Wk    = (const float*)d_in[4];
  const float* Wv    = (const float*)d_in[5];
  // d_in[6]: causal mask, handled analytically.

  float* out = (float*)d_out;

  _Float16* qh  = (_Float16*)d_ws;
  _Float16* ql  = qh  + (size_t)NB * SEQ * HD;
  _Float16* kh  = ql  + (size_t)NB * SEQ * HD;
  _Float16* kl  = kh  + (size_t)NB * SEQ * HD;
  _Float16* vt  = kl  + (size_t)NB * SEQ * HD;           // [b][64][4096]
  _Float16* wf  = vt  + (size_t)NB * SEQ * HD;           // [3][16][16][512]
  _Float16* opart = wf + (size_t)3 * 16 * 8192;          // [b*4+s][4096][64]
  float* mlp = (float*)(opart + (size_t)NB * NSPLIT * SEQ * HD);

  wsplit_kernel<<<dim3(3, 16), 256, 0, stream>>>(Wq, Wk, Wv, wf);
  proj_kernel<<<dim3(1024, 3), 64, 0, stream>>>(query, key, value, wf,
                                                qh, ql, kh, kl, vt);
  attn_kernel<<<dim3(128, NB), 256, 0, stream>>>(qh, ql, kh, kl, vt, opart, mlp);
  combine_kernel<<<1024, 256, 0, stream>>>(opart, mlp, out);
}